// Round 8
// baseline (145.379 us; speedup 1.0000x reference)
//
#include <hip/hip_runtime.h>
#include <hip/hip_cooperative_groups.h>

namespace cg = cooperative_groups;

#define BATCH 16384
#define NU 1000000
#define TBR 64           // rows per block (mfma kernel)
#define MT 512           // threads (mfma kernel), 8 waves
#define WSOFF0 0         // W0t [256][256] bf16
#define WSOFF1 65536     // W1t [128][256] bf16
#define WSOFF2 98304     // W2t [64][128]  bf16
#define WSREQ  212992    // bytes of ws needed

typedef __attribute__((ext_vector_type(8))) short short8;
typedef __attribute__((ext_vector_type(4))) short short4v;
typedef __attribute__((ext_vector_type(4))) float f32x4;

__device__ __forceinline__ unsigned short f32_bf16(float f) {
    unsigned int u = __float_as_uint(f);
    u += 0x7FFF + ((u >> 16) & 1);   // RTNE
    return (unsigned short)(u >> 16);
}
__device__ __forceinline__ float bf16_f32(unsigned short h) {
    return __uint_as_float(((unsigned int)h) << 16);
}

// XOR swizzle: 16B granule spread by row (bank-conflict-free ds_read_b128).
__device__ __forceinline__ int swz(int row, int byteInRow, int rowStrideB) {
    return row * rowStrideB + (byteInRow ^ ((row & 7) << 4));
}

__device__ __forceinline__ short8 cvt8(float4 a, float4 b) {
    short8 s;
    s[0] = (short)f32_bf16(a.x); s[1] = (short)f32_bf16(a.y);
    s[2] = (short)f32_bf16(a.z); s[3] = (short)f32_bf16(a.w);
    s[4] = (short)f32_bf16(b.x); s[5] = (short)f32_bf16(b.y);
    s[6] = (short)f32_bf16(b.z); s[7] = (short)f32_bf16(b.w);
    return s;
}

// ---- Weight-transpose slice: task g converts one u16x2 pair of Wt ----
// Total tasks: (8192 + 4096 + 1024) items x 4 pairs = 53248.
__device__ __forceinline__ void prep_slice(int g, const float* __restrict__ W0,
                                           const float* __restrict__ W1,
                                           const float* __restrict__ W2,
                                           unsigned short* __restrict__ ws) {
    if (g >= 53248) return;
    int item = g >> 2, pair = g & 3;
    const float* src; unsigned short* dst; int n, kg, K, N, K2;
    if (item < 8192)       { src = W0; dst = ws + WSOFF0; n = item >> 5;            kg = item & 31; K = 248; N = 256; K2 = 256; }
    else if (item < 12288) { int r = item - 8192;  src = W1; dst = ws + WSOFF1; n = r >> 5; kg = r & 31; K = 256; N = 128; K2 = 256; }
    else                   { int r = item - 12288; src = W2; dst = ws + WSOFF2; n = r >> 4; kg = r & 15; K = 128; N = 64;  K2 = 128; }
    int k0 = kg * 8 + pair * 2;
    float v0 = (k0 < K)     ? src[(size_t)k0 * N + n]       : 0.f;
    float v1 = (k0 + 1 < K) ? src[(size_t)(k0 + 1) * N + n] : 0.f;
    unsigned int packed = (unsigned int)f32_bf16(v0) | ((unsigned int)f32_bf16(v1) << 16);
    *(unsigned int*)(dst + (size_t)n * K2 + k0) = packed;
}

// Standalone prep kernel (fallback 2-dispatch path): 104 blocks x 512 thr.
__global__ void prep_simple(const float* __restrict__ W0, const float* __restrict__ W1,
                            const float* __restrict__ W2, unsigned short* __restrict__ ws) {
    prep_slice(blockIdx.x * 512 + threadIdx.x, W0, W1, W2, ws);
}

// ---- Main fused body (r7 structure, unchanged math) ----
__device__ __forceinline__ void wd_body(
        const int* __restrict__ user, const int* __restrict__ item,
        const float* __restrict__ genre, const float* __restrict__ tag,
        const float* __restrict__ wide_W, const float* __restrict__ wide_b,
        const float* __restrict__ user_emb, const float* __restrict__ item_emb,
        const float* __restrict__ b0, const float* __restrict__ b1,
        const float* __restrict__ b2,
        const float* __restrict__ fW, const float* __restrict__ fb,
        const unsigned short* __restrict__ ws, float* __restrict__ out,
        unsigned short* sX, unsigned short* sH0, unsigned short* sH1,
        unsigned short* sH2, unsigned short* sWide, float* sFW)
{
    const int tid = threadIdx.x;
    const int row0 = blockIdx.x * TBR;
    const unsigned short* w0t = ws + WSOFF0;
    const unsigned short* w1t = ws + WSOFF1;
    const unsigned short* w2t = ws + WSOFF2;

    const int wid = tid >> 6;
    const int lane = tid & 63;
    const int lr = lane & 15;     // row/col within 16-tile
    const int lh = lane >> 4;     // k-chunk 0..3

    // ---- Prefetch ALL weight B-fragments + biases into registers ----
    const int cb0 = wid * 32;          // L0 col strip
    const int cb1 = wid * 16;          // L1 col strip
    const int cb2 = (wid & 3) * 16;    // L2 col strip
    const int rq2 = (wid >> 2) * 16;   // L2 row-quarter within a 32-row half
    short8 B0[2][8];
    #pragma unroll
    for (int t = 0; t < 2; ++t)
        #pragma unroll
        for (int kc = 0; kc < 8; ++kc)
            B0[t][kc] = *(const short8*)(w0t + (size_t)(cb0 + t * 16 + lr) * 256 + kc * 32 + lh * 8);
    short8 B1[8];
    #pragma unroll
    for (int kc = 0; kc < 8; ++kc)
        B1[kc] = *(const short8*)(w1t + (size_t)(cb1 + lr) * 256 + kc * 32 + lh * 8);
    short8 B2f[4];
    #pragma unroll
    for (int kc = 0; kc < 4; ++kc)
        B2f[kc] = *(const short8*)(w2t + (size_t)(cb2 + lr) * 128 + kc * 32 + lh * 8);
    float rb0[2];
    rb0[0] = b0[cb0 + lr]; rb0[1] = b0[cb0 + 16 + lr];
    float rb1 = b1[cb1 + lr];
    float rb2 = b2[cb2 + lr];

    // ---- Stage x (bf16, swizzled) + wide path together: all gathers overlap ----
    #pragma unroll
    for (int it = 0; it < 6; ++it) {
        int q = tid + it * MT;
        if (it < 4) {
            int r = q >> 5, j = q & 31;
            int grow = row0 + r;
            float4 va = make_float4(0.f, 0.f, 0.f, 0.f);
            float4 vb = va;
            if (j < 8) {
                const float4* p = (const float4*)(user_emb + (size_t)user[grow] * 64);
                va = p[j * 2]; vb = p[j * 2 + 1];
            } else if (j < 16) {
                const float4* p = (const float4*)(item_emb + (size_t)item[grow] * 64);
                va = p[(j - 8) * 2]; vb = p[(j - 8) * 2 + 1];
            } else if (j == 16) {
                const float4* p = (const float4*)(genre + (size_t)grow * 20);
                va = p[0]; vb = p[1];
            } else if (j == 17) {
                const float4* p = (const float4*)(genre + (size_t)grow * 20);
                va = p[2]; vb = p[3];
            } else if (j == 18) {
                va = *(const float4*)(genre + (size_t)grow * 20 + 16);
                vb = *(const float4*)(tag + (size_t)grow * 100);
            } else if (j < 31) {
                const float4* p = (const float4*)(tag + (size_t)grow * 100 + 4);
                int jj = j - 19;
                va = p[jj * 2]; vb = p[jj * 2 + 1];
            } // j == 31: zero pad (k 248..255)
            *(short8*)((char*)sX + swz(r, j * 16, 512)) = cvt8(va, vb);
        } else {
            int p = q - 4 * MT;
            int r = p >> 4, j = p & 15;
            int grow = row0 + r;
            float4 a = ((const float4*)(wide_W + (size_t)user[grow] * 64))[j];
            float4 b = ((const float4*)(wide_W + (size_t)(NU + item[grow]) * 64))[j];
            float4 c = ((const float4*)wide_b)[j];
            short4v o;
            o[0] = (short)f32_bf16(a.x + b.x + c.x);
            o[1] = (short)f32_bf16(a.y + b.y + c.y);
            o[2] = (short)f32_bf16(a.z + b.z + c.z);
            o[3] = (short)f32_bf16(a.w + b.w + c.w);
            *(short4v*)(sWide + r * 72 + j * 4) = o;
        }
    }
    if (tid < 160) {
        ((float4*)sFW)[tid] = ((const float4*)fW)[tid];
    }

    // ---- Per-half layer bodies (h = 0: rows 0-31, h = 1: rows 32-63) ----
    auto do_L0 = [&](int h) {
        const int rb = h * 32;
        f32x4 acc[2][2];
        #pragma unroll
        for (int rt = 0; rt < 2; ++rt)
            #pragma unroll
            for (int t = 0; t < 2; ++t) acc[rt][t] = (f32x4)(0.f);
        #pragma unroll
        for (int kc = 0; kc < 8; ++kc) {
            const int kb = kc * 32 + lh * 8;
            short8 a[2];
            #pragma unroll
            for (int rt = 0; rt < 2; ++rt)
                a[rt] = *(const short8*)((const char*)sX + swz(rb + rt * 16 + lr, kb * 2, 512));
            #pragma unroll
            for (int t = 0; t < 2; ++t)
                #pragma unroll
                for (int rt = 0; rt < 2; ++rt)
                    acc[rt][t] = __builtin_amdgcn_mfma_f32_16x16x32_bf16(a[rt], B0[t][kc], acc[rt][t], 0, 0, 0);
        }
        #pragma unroll
        for (int t = 0; t < 2; ++t)
            #pragma unroll
            for (int rt = 0; rt < 2; ++rt)
                #pragma unroll
                for (int jj = 0; jj < 4; ++jj) {
                    int row = rb + rt * 16 + lh * 4 + jj;
                    float v = fmaxf(acc[rt][t][jj] + rb0[t], 0.f);
                    *(unsigned short*)((char*)sH0 + swz(row, (cb0 + t * 16 + lr) * 2, 512)) = f32_bf16(v);
                }
    };

    auto do_L1 = [&](int h) {
        const int rb = h * 32;
        f32x4 acc[2];
        acc[0] = (f32x4)(0.f); acc[1] = (f32x4)(0.f);
        #pragma unroll
        for (int kc = 0; kc < 8; ++kc) {
            const int kb = kc * 32 + lh * 8;
            short8 a[2];
            #pragma unroll
            for (int rt = 0; rt < 2; ++rt)
                a[rt] = *(const short8*)((const char*)sH0 + swz(rb + rt * 16 + lr, kb * 2, 512));
            #pragma unroll
            for (int rt = 0; rt < 2; ++rt)
                acc[rt] = __builtin_amdgcn_mfma_f32_16x16x32_bf16(a[rt], B1[kc], acc[rt], 0, 0, 0);
        }
        #pragma unroll
        for (int rt = 0; rt < 2; ++rt)
            #pragma unroll
            for (int jj = 0; jj < 4; ++jj) {
                int row = rb + rt * 16 + lh * 4 + jj;
                float v = fmaxf(acc[rt][jj] + rb1, 0.f);
                *(unsigned short*)((char*)sH1 + swz(row, (cb1 + lr) * 2, 256)) = f32_bf16(v);
            }
    };

    auto do_L2 = [&](int h) {
        const int rb = h * 32 + rq2;
        f32x4 acc = (f32x4)(0.f);
        #pragma unroll
        for (int kc = 0; kc < 4; ++kc) {
            const int kb = kc * 32 + lh * 8;
            short8 a = *(const short8*)((const char*)sH1 + swz(rb + lr, kb * 2, 256));
            acc = __builtin_amdgcn_mfma_f32_16x16x32_bf16(a, B2f[kc], acc, 0, 0, 0);
        }
        #pragma unroll
        for (int jj = 0; jj < 4; ++jj) {
            int row = rb + lh * 4 + jj;
            sH2[row * 72 + cb2 + lr] = f32_bf16(fmaxf(acc[jj] + rb2, 0.f));
        }
    };

    // ---- Pipelined phase schedule (two streams per barrier interval) ----
    __syncthreads();
    do_L0(0);
    __syncthreads();
    do_L0(1);
    do_L1(0);
    __syncthreads();
    do_L1(1);
    do_L2(0);
    __syncthreads();
    do_L2(1);
    __syncthreads();

    // ---- Final: [h2 | wide] @ fW + fb (fp32 VALU, LDS reads) ----
    if (tid < TBR * 5) {
        int r = tid / 5, c = tid - r * 5;
        float acc = fb[c];
        #pragma unroll
        for (int kq = 0; kq < 8; ++kq) {
            short8 h = *(const short8*)(sH2 + r * 72 + kq * 8);
            #pragma unroll
            for (int i = 0; i < 8; ++i)
                acc = fmaf(bf16_f32((unsigned short)h[i]), sFW[(kq * 8 + i) * 5 + c], acc);
        }
        #pragma unroll
        for (int kq = 0; kq < 8; ++kq) {
            short8 h = *(const short8*)(sWide + r * 72 + kq * 8);
            #pragma unroll
            for (int i = 0; i < 8; ++i)
                acc = fmaf(bf16_f32((unsigned short)h[i]), sFW[(64 + kq * 8 + i) * 5 + c], acc);
        }
        out[(size_t)(row0 + r) * 5 + c] = acc;
    }
}

// ---- Two-dispatch main kernel (fallback path) ----
__global__ __launch_bounds__(MT, 1) void wd_mfma(
        const int* __restrict__ user, const int* __restrict__ item,
        const float* __restrict__ genre, const float* __restrict__ tag,
        const float* __restrict__ wide_W, const float* __restrict__ wide_b,
        const float* __restrict__ user_emb, const float* __restrict__ item_emb,
        const float* __restrict__ b0, const float* __restrict__ b1,
        const float* __restrict__ b2,
        const float* __restrict__ fW, const float* __restrict__ fb,
        const unsigned short* __restrict__ ws, float* __restrict__ out)
{
    __shared__ unsigned short sX[TBR * 256];
    __shared__ unsigned short sH0[TBR * 256];
    __shared__ unsigned short sH1[TBR * 128];
    __shared__ unsigned short sH2[TBR * 72];
    __shared__ unsigned short sWide[TBR * 72];
    __shared__ float sFW[640];
    wd_body(user, item, genre, tag, wide_W, wide_b, user_emb, item_emb,
            b0, b1, b2, fW, fb, ws, out, sX, sH0, sH1, sH2, sWide, sFW);
}

// ---- Single cooperative dispatch: prep slice + grid sync + main body ----
__global__ __launch_bounds__(MT, 1) void wd_coop(
        const int* __restrict__ user, const int* __restrict__ item,
        const float* __restrict__ genre, const float* __restrict__ tag,
        const float* __restrict__ wide_W, const float* __restrict__ wide_b,
        const float* __restrict__ user_emb, const float* __restrict__ item_emb,
        const float* __restrict__ W0, const float* __restrict__ b0,
        const float* __restrict__ W1, const float* __restrict__ b1,
        const float* __restrict__ W2, const float* __restrict__ b2,
        const float* __restrict__ fW, const float* __restrict__ fb,
        unsigned short* __restrict__ ws, float* __restrict__ out)
{
    __shared__ unsigned short sX[TBR * 256];
    __shared__ unsigned short sH0[TBR * 256];
    __shared__ unsigned short sH1[TBR * 128];
    __shared__ unsigned short sH2[TBR * 72];
    __shared__ unsigned short sWide[TBR * 72];
    __shared__ float sFW[640];

    // Phase A: grid-wide weight transpose+convert into ws (blocks 0..103 active).
    prep_slice(blockIdx.x * MT + threadIdx.x, W0, W1, W2, ws);
    __threadfence();               // device-scope release of ws stores
    cg::this_grid().sync();        // all blocks see converted weights
    __threadfence();               // acquire side (cross-XCD L2)

    // Phase B: main fused body (identical to two-dispatch path).
    wd_body(user, item, genre, tag, wide_W, wide_b, user_emb, item_emb,
            b0, b1, b2, fW, fb, ws, out, sX, sH0, sH1, sH2, sWide, sFW);
}

// ================= fp32 fallback (used if ws too small) =================
#define NTHR 256
#define TB 32

__device__ __forceinline__ void fma4(float4& a, float s, const float4& w) {
    a.x = fmaf(s, w.x, a.x); a.y = fmaf(s, w.y, a.y);
    a.z = fmaf(s, w.z, a.z); a.w = fmaf(s, w.w, a.w);
}
__device__ __forceinline__ float4 add4(const float4& a, const float4& b) {
    return make_float4(a.x + b.x, a.y + b.y, a.z + b.z, a.w + b.w);
}
__device__ __forceinline__ float4 relu4(const float4& a) {
    return make_float4(fmaxf(a.x, 0.f), fmaxf(a.y, 0.f), fmaxf(a.z, 0.f), fmaxf(a.w, 0.f));
}

__global__ void wd_fused(const int* __restrict__ user, const int* __restrict__ item,
                         const float* __restrict__ genre, const float* __restrict__ tag,
                         const float* __restrict__ wide_W, const float* __restrict__ wide_b,
                         const float* __restrict__ user_emb, const float* __restrict__ item_emb,
                         const float* __restrict__ W0, const float* __restrict__ b0,
                         const float* __restrict__ W1, const float* __restrict__ b1,
                         const float* __restrict__ W2, const float* __restrict__ b2,
                         const float* __restrict__ fW, const float* __restrict__ fb,
                         float* __restrict__ out)
{
    __shared__ float sA[TB * 248];
    __shared__ float sB[TB * 256];
    __shared__ float sC[TB * 64];

    const int tid = threadIdx.x;
    const int row0 = blockIdx.x * TB;

    for (int q = tid; q < TB * 62; q += NTHR) {
        int r = q / 62, j = q - r * 62, grow = row0 + r;
        float4 v;
        if (j < 16) v = reinterpret_cast<const float4*>(user_emb + (size_t)user[grow] * 64)[j];
        else if (j < 32) v = reinterpret_cast<const float4*>(item_emb + (size_t)item[grow] * 64)[j - 16];
        else if (j < 37) v = reinterpret_cast<const float4*>(genre + (size_t)grow * 20)[j - 32];
        else v = reinterpret_cast<const float4*>(tag + (size_t)grow * 100)[j - 37];
        *reinterpret_cast<float4*>(sA + r * 248 + j * 4) = v;
    }
    for (int q = tid; q < TB * 16; q += NTHR) {
        int r = q >> 4, j = q & 15, grow = row0 + r;
        float4 a = reinterpret_cast<const float4*>(wide_W + (size_t)user[grow] * 64)[j];
        float4 b = reinterpret_cast<const float4*>(wide_W + (size_t)(NU + item[grow]) * 64)[j];
        float4 c = reinterpret_cast<const float4*>(wide_b)[j];
        *reinterpret_cast<float4*>(sC + r * 64 + j * 4) =
            make_float4(a.x + b.x + c.x, a.y + b.y + c.y, a.z + b.z + c.z, a.w + b.w + c.w);
    }
    __syncthreads();
    {
        const int cg_ = tid & 63, r0 = (tid >> 6) * 8;
        float4 acc[8];
        #pragma unroll
        for (int r = 0; r < 8; ++r) acc[r] = make_float4(0.f, 0.f, 0.f, 0.f);
        for (int k = 0; k < 248; k += 4) {
            const float4* wp = reinterpret_cast<const float4*>(W0 + (size_t)k * 256) + cg_;
            float4 w0 = wp[0], w1 = wp[64], w2 = wp[128], w3 = wp[192];
            #pragma unroll
            for (int r = 0; r < 8; ++r) {
                float4 xv = *reinterpret_cast<const float4*>(sA + (r0 + r) * 248 + k);
                fma4(acc[r], xv.x, w0); fma4(acc[r], xv.y, w1);
                fma4(acc[r], xv.z, w2); fma4(acc[r], xv.w, w3);
            }
        }
        float4 bb = reinterpret_cast<const float4*>(b0)[cg_];
        #pragma unroll
        for (int r = 0; r < 8; ++r)
            *reinterpret_cast<float4*>(sB + (r0 + r) * 256 + cg_ * 4) = relu4(add4(acc[r], bb));
    }
    __syncthreads();
    {
        const int cg_ = tid & 31, r0 = (tid >> 5) * 4;
        float4 acc[4];
        #pragma unroll
        for (int r = 0; r < 4; ++r) acc[r] = make_float4(0.f, 0.f, 0.f, 0.f);
        for (int k = 0; k < 256; k += 4) {
            const float4* wp = reinterpret_cast<const float4*>(W1 + (size_t)k * 128) + cg_;
            float4 w0 = wp[0], w1 = wp[32], w2 = wp[64], w3 = wp[96];
            #pragma unroll
            for (int r = 0; r < 4; ++r) {
                float4 xv = *reinterpret_cast<const float4*>(sB + (r0 + r) * 256 + k);
                fma4(acc[r], xv.x, w0); fma4(acc[r], xv.y, w1);
                fma4(acc[r], xv.z, w2); fma4(acc[r], xv.w, w3);
            }
        }
        float4 bb = reinterpret_cast<const float4*>(b1)[cg_];
        #pragma unroll
        for (int r = 0; r < 4; ++r)
            *reinterpret_cast<float4*>(sA + (r0 + r) * 128 + cg_ * 4) = relu4(add4(acc[r], bb));
    }
    __syncthreads();
    {
        const int cg_ = tid & 15, r0 = (tid >> 4) * 2;
        float4 acc[2];
        acc[0] = make_float4(0.f, 0.f, 0.f, 0.f); acc[1] = acc[0];
        for (int k = 0; k < 128; k += 4) {
            const float4* wp = reinterpret_cast<const float4*>(W2 + (size_t)k * 64) + cg_;
            float4 w0 = wp[0], w1 = wp[16], w2 = wp[32], w3 = wp[48];
            #pragma unroll
            for (int r = 0; r < 2; ++r) {
                float4 xv = *reinterpret_cast<const float4*>(sA + (r0 + r) * 128 + k);
                fma4(acc[r], xv.x, w0); fma4(acc[r], xv.y, w1);
                fma4(acc[r], xv.z, w2); fma4(acc[r], xv.w, w3);
            }
        }
        float4 bb = reinterpret_cast<const float4*>(b2)[cg_];
        #pragma unroll
        for (int r = 0; r < 2; ++r)
            *reinterpret_cast<float4*>(sB + (r0 + r) * 64 + cg_ * 4) = relu4(add4(acc[r], bb));
    }
    __syncthreads();
    if (tid < TB * 5) {
        int r = tid / 5, c = tid - r * 5;
        float acc = fb[c];
        for (int k = 0; k < 64; ++k) acc = fmaf(sB[r * 64 + k], fW[k * 5 + c], acc);
        for (int k = 0; k < 64; ++k) acc = fmaf(sC[r * 64 + k], fW[(64 + k) * 5 + c], acc);
        out[(size_t)(row0 + r) * 5 + c] = acc;
    }
}

extern "C" void kernel_launch(void* const* d_in, const int* in_sizes, int n_in,
                              void* d_out, int out_size, void* d_ws, size_t ws_size,
                              hipStream_t stream) {
    const int* user = (const int*)d_in[0];
    const int* item = (const int*)d_in[1];
    const float* genre = (const float*)d_in[2];
    const float* tag = (const float*)d_in[3];
    const float* wide_W = (const float*)d_in[4];
    const float* wide_b = (const float*)d_in[5];
    const float* user_emb = (const float*)d_in[6];
    const float* item_emb = (const float*)d_in[7];
    const float* W0 = (const float*)d_in[8];
    const float* b0 = (const float*)d_in[9];
    const float* W1 = (const float*)d_in[10];
    const float* b1 = (const float*)d_in[11];
    const float* W2 = (const float*)d_in[12];
    const float* b2 = (const float*)d_in[13];
    const float* fW = (const float*)d_in[14];
    const float* fb = (const float*)d_in[15];
    float* out = (float*)d_out;

    if (ws_size >= (size_t)WSREQ) {
        unsigned short* ws = (unsigned short*)d_ws;
        void* args[18] = {
            (void*)&user, (void*)&item, (void*)&genre, (void*)&tag,
            (void*)&wide_W, (void*)&wide_b, (void*)&user_emb, (void*)&item_emb,
            (void*)&W0, (void*)&b0, (void*)&W1, (void*)&b1,
            (void*)&W2, (void*)&b2, (void*)&fW, (void*)&fb,
            (void*)&ws, (void*)&out
        };
        hipError_t e = hipLaunchCooperativeKernel((const void*)wd_coop,
                                                  dim3(BATCH / TBR), dim3(MT),
                                                  args, 0, stream);
        if (e != hipSuccess) {
            // Fallback: proven two-dispatch path.
            hipLaunchKernelGGL(prep_simple, dim3(104), dim3(512), 0, stream,
                               W0, W1, W2, ws);
            hipLaunchKernelGGL(wd_mfma, dim3(BATCH / TBR), dim3(MT), 0, stream,
                               user, item, genre, tag, wide_W, wide_b, user_emb, item_emb,
                               b0, b1, b2, fW, fb, ws, out);
        }
    } else {
        hipLaunchKernelGGL(wd_fused, dim3(BATCH / TB), dim3(NTHR), 0, stream,
                           user, item, genre, tag, wide_W, wide_b, user_emb, item_emb,
                           W0, b0, W1, b1, W2, b2, fW, fb, out);
    }
}

// Round 9
// 30.354 us; speedup vs baseline: 4.7895x; 4.7895x over previous
//
#include <hip/hip_runtime.h>

#define BATCH 16384
#define NU 1000000
#define TBR 64           // rows per block (mfma kernel)
#define MT 1024          // threads (mfma kernel), 16 waves -> 4 waves/SIMD
#define WSOFF0 0         // W0t [256][256] bf16
#define WSOFF1 65536     // W1t [128][256] bf16
#define WSOFF2 98304     // W2t [64][128]  bf16
#define WSREQ  212992    // bytes of ws needed

typedef __attribute__((ext_vector_type(8))) short short8;
typedef __attribute__((ext_vector_type(4))) short short4v;
typedef __attribute__((ext_vector_type(4))) float f32x4;

__device__ __forceinline__ unsigned short f32_bf16(float f) {
    unsigned int u = __float_as_uint(f);
    u += 0x7FFF + ((u >> 16) & 1);   // RTNE
    return (unsigned short)(u >> 16);
}
__device__ __forceinline__ float bf16_f32(unsigned short h) {
    return __uint_as_float(((unsigned int)h) << 16);
}

// XOR swizzle: 16B granule spread by row (bank-conflict-free ds_read_b128).
__device__ __forceinline__ int swz(int row, int byteInRow, int rowStrideB) {
    return row * rowStrideB + (byteInRow ^ ((row & 7) << 4));
}

__device__ __forceinline__ short8 cvt8(float4 a, float4 b) {
    short8 s;
    s[0] = (short)f32_bf16(a.x); s[1] = (short)f32_bf16(a.y);
    s[2] = (short)f32_bf16(a.z); s[3] = (short)f32_bf16(a.w);
    s[4] = (short)f32_bf16(b.x); s[5] = (short)f32_bf16(b.y);
    s[6] = (short)f32_bf16(b.z); s[7] = (short)f32_bf16(b.w);
    return s;
}

// ---- Weight-transpose slice: task g converts one u16x2 pair of Wt ----
__device__ __forceinline__ void prep_slice(int g, const float* __restrict__ W0,
                                           const float* __restrict__ W1,
                                           const float* __restrict__ W2,
                                           unsigned short* __restrict__ ws) {
    if (g >= 53248) return;
    int item = g >> 2, pair = g & 3;
    const float* src; unsigned short* dst; int n, kg, K, N, K2;
    if (item < 8192)       { src = W0; dst = ws + WSOFF0; n = item >> 5;            kg = item & 31; K = 248; N = 256; K2 = 256; }
    else if (item < 12288) { int r = item - 8192;  src = W1; dst = ws + WSOFF1; n = r >> 5; kg = r & 31; K = 256; N = 128; K2 = 256; }
    else                   { int r = item - 12288; src = W2; dst = ws + WSOFF2; n = r >> 4; kg = r & 15; K = 128; N = 64;  K2 = 128; }
    int k0 = kg * 8 + pair * 2;
    float v0 = (k0 < K)     ? src[(size_t)k0 * N + n]       : 0.f;
    float v1 = (k0 + 1 < K) ? src[(size_t)(k0 + 1) * N + n] : 0.f;
    unsigned int packed = (unsigned int)f32_bf16(v0) | ((unsigned int)f32_bf16(v1) << 16);
    *(unsigned int*)(dst + (size_t)n * K2 + k0) = packed;
}

// Prep kernel: 104 blocks x 512 thr.
__global__ void prep_simple(const float* __restrict__ W0, const float* __restrict__ W1,
                            const float* __restrict__ W2, unsigned short* __restrict__ ws) {
    prep_slice(blockIdx.x * 512 + threadIdx.x, W0, W1, W2, ws);
}

// ---- Main fused MFMA kernel: 256 blocks x 1024 thr, 64 rows/block ----
// 16 waves: L0 wave = 16-col strip; L1 wave = (8 col-strips x 2 row-halves);
// L2 wave = (4 col-strips x 4 row-quarters).
__global__ __launch_bounds__(MT) void wd_mfma(
        const int* __restrict__ user, const int* __restrict__ item,
        const float* __restrict__ genre, const float* __restrict__ tag,
        const float* __restrict__ wide_W, const float* __restrict__ wide_b,
        const float* __restrict__ user_emb, const float* __restrict__ item_emb,
        const float* __restrict__ b0, const float* __restrict__ b1,
        const float* __restrict__ b2,
        const float* __restrict__ fW, const float* __restrict__ fb,
        const unsigned short* __restrict__ ws, float* __restrict__ out)
{
    __shared__ unsigned short sX[TBR * 256];   // x tile bf16 (swizzled, 512B rows)
    __shared__ unsigned short sH0[TBR * 256];  // h0 bf16 (swizzled, 512B rows)
    __shared__ unsigned short sH1[TBR * 128];  // h1 bf16 (swizzled, 256B rows)
    __shared__ unsigned short sH2[TBR * 72];   // h2 bf16 (stride 72)
    __shared__ unsigned short sWide[TBR * 72]; // wide bf16 (stride 72)
    __shared__ float sFW[640];                 // fW fp32

    const int tid = threadIdx.x;
    const int row0 = blockIdx.x * TBR;
    const unsigned short* w0t = ws + WSOFF0;
    const unsigned short* w1t = ws + WSOFF1;
    const unsigned short* w2t = ws + WSOFF2;

    const int wid = tid >> 6;     // 0..15
    const int lane = tid & 63;
    const int lr = lane & 15;     // row/col within 16-tile
    const int lh = lane >> 4;     // k-chunk 0..3

    // Wave work assignments
    const int cb0 = wid * 16;              // L0: 16 strips x 16 cols = 256
    const int s1 = wid & 7, h1 = wid >> 3; // L1: 8 strips x 2 row-halves
    const int cb1 = s1 * 16;
    const int s2 = wid & 3, q2 = wid >> 2; // L2: 4 strips x 4 row-quarters
    const int cb2 = s2 * 16;

    // ---- Prefetch L0 B-fragments + biases (pre-barrier; B1/B2 post-barrier) ----
    short8 B0[8];
    #pragma unroll
    for (int kc = 0; kc < 8; ++kc)
        B0[kc] = *(const short8*)(w0t + (size_t)(cb0 + lr) * 256 + kc * 32 + lh * 8);
    float rb0 = b0[cb0 + lr];
    float rb1 = b1[cb1 + lr];
    float rb2 = b2[cb2 + lr];

    // ---- Stage x (bf16, swizzled) + wide path: 3 iterations total ----
    #pragma unroll
    for (int it = 0; it < 2; ++it) {
        int q = tid + it * MT;
        int r = q >> 5, j = q & 31;
        int grow = row0 + r;
        float4 va = make_float4(0.f, 0.f, 0.f, 0.f);
        float4 vb = va;
        if (j < 8) {
            const float4* p = (const float4*)(user_emb + (size_t)user[grow] * 64);
            va = p[j * 2]; vb = p[j * 2 + 1];
        } else if (j < 16) {
            const float4* p = (const float4*)(item_emb + (size_t)item[grow] * 64);
            va = p[(j - 8) * 2]; vb = p[(j - 8) * 2 + 1];
        } else if (j == 16) {
            const float4* p = (const float4*)(genre + (size_t)grow * 20);
            va = p[0]; vb = p[1];
        } else if (j == 17) {
            const float4* p = (const float4*)(genre + (size_t)grow * 20);
            va = p[2]; vb = p[3];
        } else if (j == 18) {
            va = *(const float4*)(genre + (size_t)grow * 20 + 16);
            vb = *(const float4*)(tag + (size_t)grow * 100);
        } else if (j < 31) {
            const float4* p = (const float4*)(tag + (size_t)grow * 100 + 4);
            int jj = j - 19;
            va = p[jj * 2]; vb = p[jj * 2 + 1];
        } // j == 31: zero pad (k 248..255)
        *(short8*)((char*)sX + swz(r, j * 16, 512)) = cvt8(va, vb);
    }
    {
        int r = tid >> 4, j = tid & 15;
        int grow = row0 + r;
        float4 a = ((const float4*)(wide_W + (size_t)user[grow] * 64))[j];
        float4 b = ((const float4*)(wide_W + (size_t)(NU + item[grow]) * 64))[j];
        float4 c = ((const float4*)wide_b)[j];
        short4v o;
        o[0] = (short)f32_bf16(a.x + b.x + c.x);
        o[1] = (short)f32_bf16(a.y + b.y + c.y);
        o[2] = (short)f32_bf16(a.z + b.z + c.z);
        o[3] = (short)f32_bf16(a.w + b.w + c.w);
        *(short4v*)(sWide + r * 72 + j * 4) = o;
    }
    if (tid < 160) {
        ((float4*)sFW)[tid] = ((const float4*)fW)[tid];
    }
    __syncthreads();

    // ---- Layer 0: x[64][256] @ W0t -> h0[64][256] (wave = 16-col strip, 4 row-tiles) ----
    {
        f32x4 acc[4];
        #pragma unroll
        for (int rt = 0; rt < 4; ++rt) acc[rt] = (f32x4)(0.f);
        #pragma unroll
        for (int kc = 0; kc < 8; ++kc) {
            const int kb = kc * 32 + lh * 8;
            #pragma unroll
            for (int rt = 0; rt < 4; ++rt) {
                short8 a = *(const short8*)((const char*)sX + swz(rt * 16 + lr, kb * 2, 512));
                acc[rt] = __builtin_amdgcn_mfma_f32_16x16x32_bf16(a, B0[kc], acc[rt], 0, 0, 0);
            }
        }
        #pragma unroll
        for (int rt = 0; rt < 4; ++rt)
            #pragma unroll
            for (int jj = 0; jj < 4; ++jj) {
                int row = rt * 16 + lh * 4 + jj;
                float v = fmaxf(acc[rt][jj] + rb0, 0.f);
                *(unsigned short*)((char*)sH0 + swz(row, (cb0 + lr) * 2, 512)) = f32_bf16(v);
            }
        __syncthreads();
    }

    // ---- Layer 1: h0[64][256] @ W1t -> h1[64][128] (wave = 16-col strip x 32-row half) ----
    {
        f32x4 acc[2];
        acc[0] = (f32x4)(0.f); acc[1] = (f32x4)(0.f);
        #pragma unroll
        for (int kc = 0; kc < 8; ++kc) {
            const int kb = kc * 32 + lh * 8;
            short8 bf = *(const short8*)(w1t + (size_t)(cb1 + lr) * 256 + kb);
            #pragma unroll
            for (int rt = 0; rt < 2; ++rt) {
                short8 a = *(const short8*)((const char*)sH0 + swz(h1 * 32 + rt * 16 + lr, kb * 2, 512));
                acc[rt] = __builtin_amdgcn_mfma_f32_16x16x32_bf16(a, bf, acc[rt], 0, 0, 0);
            }
        }
        #pragma unroll
        for (int rt = 0; rt < 2; ++rt)
            #pragma unroll
            for (int jj = 0; jj < 4; ++jj) {
                int row = h1 * 32 + rt * 16 + lh * 4 + jj;
                float v = fmaxf(acc[rt][jj] + rb1, 0.f);
                *(unsigned short*)((char*)sH1 + swz(row, (cb1 + lr) * 2, 256)) = f32_bf16(v);
            }
        __syncthreads();
    }

    // ---- Layer 2: h1[64][128] @ W2t -> h2[64][64] (wave = 16-col strip x 16-row quarter) ----
    {
        f32x4 acc = (f32x4)(0.f);
        #pragma unroll
        for (int kc = 0; kc < 4; ++kc) {
            const int kb = kc * 32 + lh * 8;
            short8 bf = *(const short8*)(w2t + (size_t)(cb2 + lr) * 128 + kb);
            short8 a = *(const short8*)((const char*)sH1 + swz(q2 * 16 + lr, kb * 2, 256));
            acc = __builtin_amdgcn_mfma_f32_16x16x32_bf16(a, bf, acc, 0, 0, 0);
        }
        #pragma unroll
        for (int jj = 0; jj < 4; ++jj) {
            int row = q2 * 16 + lh * 4 + jj;
            sH2[row * 72 + cb2 + lr] = f32_bf16(fmaxf(acc[jj] + rb2, 0.f));
        }
        __syncthreads();
    }

    // ---- Final: [h2 | wide] @ fW + fb (fp32 VALU, LDS reads) ----
    if (tid < TBR * 5) {
        int r = tid / 5, c = tid - r * 5;
        float acc = fb[c];
        #pragma unroll
        for (int kq = 0; kq < 8; ++kq) {
            short8 h = *(const short8*)(sH2 + r * 72 + kq * 8);
            #pragma unroll
            for (int i = 0; i < 8; ++i)
                acc = fmaf(bf16_f32((unsigned short)h[i]), sFW[(kq * 8 + i) * 5 + c], acc);
        }
        #pragma unroll
        for (int kq = 0; kq < 8; ++kq) {
            short8 h = *(const short8*)(sWide + r * 72 + kq * 8);
            #pragma unroll
            for (int i = 0; i < 8; ++i)
                acc = fmaf(bf16_f32((unsigned short)h[i]), sFW[(64 + kq * 8 + i) * 5 + c], acc);
        }
        out[(size_t)(row0 + r) * 5 + c] = acc;
    }
}

// ================= fp32 fallback (used if ws too small) =================
#define NTHR 256
#define TB 32

__device__ __forceinline__ void fma4(float4& a, float s, const float4& w) {
    a.x = fmaf(s, w.x, a.x); a.y = fmaf(s, w.y, a.y);
    a.z = fmaf(s, w.z, a.z); a.w = fmaf(s, w.w, a.w);
}
__device__ __forceinline__ float4 add4(const float4& a, const float4& b) {
    return make_float4(a.x + b.x, a.y + b.y, a.z + b.z, a.w + b.w);
}
__device__ __forceinline__ float4 relu4(const float4& a) {
    return make_float4(fmaxf(a.x, 0.f), fmaxf(a.y, 0.f), fmaxf(a.z, 0.f), fmaxf(a.w, 0.f));
}

__global__ void wd_fused(const int* __restrict__ user, const int* __restrict__ item,
                         const float* __restrict__ genre, const float* __restrict__ tag,
                         const float* __restrict__ wide_W, const float* __restrict__ wide_b,
                         const float* __restrict__ user_emb, const float* __restrict__ item_emb,
                         const float* __restrict__ W0, const float* __restrict__ b0,
                         const float* __restrict__ W1, const float* __restrict__ b1,
                         const float* __restrict__ W2, const float* __restrict__ b2,
                         const float* __restrict__ fW, const float* __restrict__ fb,
                         float* __restrict__ out)
{
    __shared__ float sA[TB * 248];
    __shared__ float sB[TB * 256];
    __shared__ float sC[TB * 64];

    const int tid = threadIdx.x;
    const int row0 = blockIdx.x * TB;

    for (int q = tid; q < TB * 62; q += NTHR) {
        int r = q / 62, j = q - r * 62, grow = row0 + r;
        float4 v;
        if (j < 16) v = reinterpret_cast<const float4*>(user_emb + (size_t)user[grow] * 64)[j];
        else if (j < 32) v = reinterpret_cast<const float4*>(item_emb + (size_t)item[grow] * 64)[j - 16];
        else if (j < 37) v = reinterpret_cast<const float4*>(genre + (size_t)grow * 20)[j - 32];
        else v = reinterpret_cast<const float4*>(tag + (size_t)grow * 100)[j - 37];
        *reinterpret_cast<float4*>(sA + r * 248 + j * 4) = v;
    }
    for (int q = tid; q < TB * 16; q += NTHR) {
        int r = q >> 4, j = q & 15, grow = row0 + r;
        float4 a = reinterpret_cast<const float4*>(wide_W + (size_t)user[grow] * 64)[j];
        float4 b = reinterpret_cast<const float4*>(wide_W + (size_t)(NU + item[grow]) * 64)[j];
        float4 c = reinterpret_cast<const float4*>(wide_b)[j];
        *reinterpret_cast<float4*>(sC + r * 64 + j * 4) =
            make_float4(a.x + b.x + c.x, a.y + b.y + c.y, a.z + b.z + c.z, a.w + b.w + c.w);
    }
    __syncthreads();
    {
        const int cg = tid & 63, r0 = (tid >> 6) * 8;
        float4 acc[8];
        #pragma unroll
        for (int r = 0; r < 8; ++r) acc[r] = make_float4(0.f, 0.f, 0.f, 0.f);
        for (int k = 0; k < 248; k += 4) {
            const float4* wp = reinterpret_cast<const float4*>(W0 + (size_t)k * 256) + cg;
            float4 w0 = wp[0], w1 = wp[64], w2 = wp[128], w3 = wp[192];
            #pragma unroll
            for (int r = 0; r < 8; ++r) {
                float4 xv = *reinterpret_cast<const float4*>(sA + (r0 + r) * 248 + k);
                fma4(acc[r], xv.x, w0); fma4(acc[r], xv.y, w1);
                fma4(acc[r], xv.z, w2); fma4(acc[r], xv.w, w3);
            }
        }
        float4 bb = reinterpret_cast<const float4*>(b0)[cg];
        #pragma unroll
        for (int r = 0; r < 8; ++r)
            *reinterpret_cast<float4*>(sB + (r0 + r) * 256 + cg * 4) = relu4(add4(acc[r], bb));
    }
    __syncthreads();
    {
        const int cg = tid & 31, r0 = (tid >> 5) * 4;
        float4 acc[4];
        #pragma unroll
        for (int r = 0; r < 4; ++r) acc[r] = make_float4(0.f, 0.f, 0.f, 0.f);
        for (int k = 0; k < 256; k += 4) {
            const float4* wp = reinterpret_cast<const float4*>(W1 + (size_t)k * 128) + cg;
            float4 w0 = wp[0], w1 = wp[32], w2 = wp[64], w3 = wp[96];
            #pragma unroll
            for (int r = 0; r < 4; ++r) {
                float4 xv = *reinterpret_cast<const float4*>(sB + (r0 + r) * 256 + k);
                fma4(acc[r], xv.x, w0); fma4(acc[r], xv.y, w1);
                fma4(acc[r], xv.z, w2); fma4(acc[r], xv.w, w3);
            }
        }
        float4 bb = reinterpret_cast<const float4*>(b1)[cg];
        #pragma unroll
        for (int r = 0; r < 4; ++r)
            *reinterpret_cast<float4*>(sA + (r0 + r) * 128 + cg * 4) = relu4(add4(acc[r], bb));
    }
    __syncthreads();
    {
        const int cg = tid & 15, r0 = (tid >> 4) * 2;
        float4 acc[2];
        acc[0] = make_float4(0.f, 0.f, 0.f, 0.f); acc[1] = acc[0];
        for (int k = 0; k < 128; k += 4) {
            const float4* wp = reinterpret_cast<const float4*>(W2 + (size_t)k * 64) + cg;
            float4 w0 = wp[0], w1 = wp[16], w2 = wp[32], w3 = wp[48];
            #pragma unroll
            for (int r = 0; r < 2; ++r) {
                float4 xv = *reinterpret_cast<const float4*>(sA + (r0 + r) * 128 + k);
                fma4(acc[r], xv.x, w0); fma4(acc[r], xv.y, w1);
                fma4(acc[r], xv.z, w2); fma4(acc[r], xv.w, w3);
            }
        }
        float4 bb = reinterpret_cast<const float4*>(b2)[cg];
        #pragma unroll
        for (int r = 0; r < 2; ++r)
            *reinterpret_cast<float4*>(sB + (r0 + r) * 64 + cg * 4) = relu4(add4(acc[r], bb));
    }
    __syncthreads();
    if (tid < TB * 5) {
        int r = tid / 5, c = tid - r * 5;
        float acc = fb[c];
        for (int k = 0; k < 64; ++k) acc = fmaf(sB[r * 64 + k], fW[k * 5 + c], acc);
        for (int k = 0; k < 64; ++k) acc = fmaf(sC[r * 64 + k], fW[(64 + k) * 5 + c], acc);
        out[(size_t)(row0 + r) * 5 + c] = acc;
    }
}

extern "C" void kernel_launch(void* const* d_in, const int* in_sizes, int n_in,
                              void* d_out, int out_size, void* d_ws, size_t ws_size,
                              hipStream_t stream) {
    const int* user = (const int*)d_in[0];
    const int* item = (const int*)d_in[1];
    const float* genre = (const float*)d_in[2];
    const float* tag = (const float*)d_in[3];
    const float* wide_W = (const float*)d_in[4];
    const float* wide_b = (const float*)d_in[5];
    const float* user_emb = (const float*)d_in[6];
    const float* item_emb = (const float*)d_in[7];
    const float* W0 = (const float*)d_in[8];
    const float* b0 = (const float*)d_in[9];
    const float* W1 = (const float*)d_in[10];
    const float* b1 = (const float*)d_in[11];
    const float* W2 = (const float*)d_in[12];
    const float* b2 = (const float*)d_in[13];
    const float* fW = (const float*)d_in[14];
    const float* fb = (const float*)d_in[15];
    float* out = (float*)d_out;

    if (ws_size >= (size_t)WSREQ) {
        unsigned short* ws = (unsigned short*)d_ws;
        hipLaunchKernelGGL(prep_simple, dim3(104), dim3(512), 0, stream,
                           W0, W1, W2, ws);
        hipLaunchKernelGGL(wd_mfma, dim3(BATCH / TBR), dim3(MT), 0, stream,
                           user, item, genre, tag, wide_W, wide_b, user_emb, item_emb,
                           b0, b1, b2, fW, fb, ws, out);
    } else {
        hipLaunchKernelGGL(wd_fused, dim3(BATCH / TB), dim3(NTHR), 0, stream,
                           user, item, genre, tag, wide_W, wide_b, user_emb, item_emb,
                           W0, b0, W1, b1, W2, b2, fW, fb, out);
    }
}

// Round 10
// 29.947 us; speedup vs baseline: 4.8546x; 1.0136x over previous
//
#include <hip/hip_runtime.h>

#define BATCH 16384
#define NU 1000000
#define TBR 64           // rows per block (mfma kernel)
#define MT 1024          // threads (mfma kernel), 16 waves -> 4 waves/SIMD
#define WSOFF0 0         // W0t [256][256] bf16
#define WSOFF1 65536     // W1t [128][256] bf16
#define WSOFF2 98304     // W2t [64][128]  bf16
#define WSREQ  212992    // bytes of ws needed

// Fragment-major LDS addressing: 16B slot s -> byte offset with 1/8 padding.
// bank-quad(s) = ((s>>3) + (s&7)) % 8 sweeps all quads across 8-lane groups.
#define FSLOT(s) (((s) << 4) + (((s) >> 3) << 4))

typedef __attribute__((ext_vector_type(8))) short short8;
typedef __attribute__((ext_vector_type(4))) short short4v;
typedef __attribute__((ext_vector_type(4))) float f32x4;

__device__ __forceinline__ unsigned short f32_bf16(float f) {
    unsigned int u = __float_as_uint(f);
    u += 0x7FFF + ((u >> 16) & 1);   // RTNE
    return (unsigned short)(u >> 16);
}
__device__ __forceinline__ float bf16_f32(unsigned short h) {
    return __uint_as_float(((unsigned int)h) << 16);
}

__device__ __forceinline__ short8 cvt8(float4 a, float4 b) {
    short8 s;
    s[0] = (short)f32_bf16(a.x); s[1] = (short)f32_bf16(a.y);
    s[2] = (short)f32_bf16(a.z); s[3] = (short)f32_bf16(a.w);
    s[4] = (short)f32_bf16(b.x); s[5] = (short)f32_bf16(b.y);
    s[6] = (short)f32_bf16(b.z); s[7] = (short)f32_bf16(b.w);
    return s;
}

// ---- Weight-transpose slice: task g converts one u16x2 pair of Wt ----
__device__ __forceinline__ void prep_slice(int g, const float* __restrict__ W0,
                                           const float* __restrict__ W1,
                                           const float* __restrict__ W2,
                                           unsigned short* __restrict__ ws) {
    if (g >= 53248) return;
    int item = g >> 2, pair = g & 3;
    const float* src; unsigned short* dst; int n, kg, K, N, K2;
    if (item < 8192)       { src = W0; dst = ws + WSOFF0; n = item >> 5;            kg = item & 31; K = 248; N = 256; K2 = 256; }
    else if (item < 12288) { int r = item - 8192;  src = W1; dst = ws + WSOFF1; n = r >> 5; kg = r & 31; K = 256; N = 128; K2 = 256; }
    else                   { int r = item - 12288; src = W2; dst = ws + WSOFF2; n = r >> 4; kg = r & 15; K = 128; N = 64;  K2 = 128; }
    int k0 = kg * 8 + pair * 2;
    float v0 = (k0 < K)     ? src[(size_t)k0 * N + n]       : 0.f;
    float v1 = (k0 + 1 < K) ? src[(size_t)(k0 + 1) * N + n] : 0.f;
    unsigned int packed = (unsigned int)f32_bf16(v0) | ((unsigned int)f32_bf16(v1) << 16);
    *(unsigned int*)(dst + (size_t)n * K2 + k0) = packed;
}

// Prep kernel: 104 blocks x 512 thr.
__global__ void prep_simple(const float* __restrict__ W0, const float* __restrict__ W1,
                            const float* __restrict__ W2, unsigned short* __restrict__ ws) {
    prep_slice(blockIdx.x * 512 + threadIdx.x, W0, W1, W2, ws);
}

// ---- Main fused MFMA kernel: 256 blocks x 1024 thr, 64 rows/block ----
// sX/sH0/sH1 in fragment-major layout: A-frag of (rt,kc) for lane l lives at
// FSLOT(base(rt,kc) + l), base(rt,kc) = (rt*KC + kc)*64 -> lane-linear reads.
__global__ __launch_bounds__(MT) void wd_mfma(
        const int* __restrict__ user, const int* __restrict__ item,
        const float* __restrict__ genre, const float* __restrict__ tag,
        const float* __restrict__ wide_W, const float* __restrict__ wide_b,
        const float* __restrict__ user_emb, const float* __restrict__ item_emb,
        const float* __restrict__ b0, const float* __restrict__ b1,
        const float* __restrict__ b2,
        const float* __restrict__ fW, const float* __restrict__ fb,
        const unsigned short* __restrict__ ws, float* __restrict__ out)
{
    __shared__ char sX[36864];                 // x  [4rt][8kc] frag-major (padded)
    __shared__ char sH0[36864];                // h0 [4rt][8kc] frag-major
    __shared__ char sH1[18432];                // h1 [4rt][4kc] frag-major
    __shared__ unsigned short sH2[TBR * 72];   // h2 bf16 (stride 72)
    __shared__ unsigned short sWide[TBR * 72]; // wide bf16 (stride 72)
    __shared__ float sFW[640];                 // fW fp32

    const int tid = threadIdx.x;
    const int row0 = blockIdx.x * TBR;
    const unsigned short* w0t = ws + WSOFF0;
    const unsigned short* w1t = ws + WSOFF1;
    const unsigned short* w2t = ws + WSOFF2;

    const int wid = tid >> 6;     // 0..15
    const int lane = tid & 63;
    const int lr = lane & 15;     // row/col within 16-tile
    const int lh = lane >> 4;     // k-chunk 0..3
    const int aoff = FSLOT(lane); // per-lane A-frag byte offset (lane-linear)

    // Wave work assignments
    const int cb0 = wid * 16;              // L0: 16 strips x 16 cols = 256
    const int s1 = wid & 7, h1 = wid >> 3; // L1: 8 strips x 2 row-halves
    const int cb1 = s1 * 16;
    const int s2 = wid & 3, q2 = wid >> 2; // L2: 4 strips x 4 row-quarters
    const int cb2 = s2 * 16;

    // ---- Prefetch L0 B-fragments + biases (pre-barrier; B1/B2 post-barrier) ----
    short8 B0[8];
    #pragma unroll
    for (int kc = 0; kc < 8; ++kc)
        B0[kc] = *(const short8*)(w0t + (size_t)(cb0 + lr) * 256 + kc * 32 + lh * 8);
    float rb0 = b0[cb0 + lr];
    float rb1 = b1[cb1 + lr];
    float rb2 = b2[cb2 + lr];

    // ---- Stage x (bf16, frag-major) + wide path ----
    #pragma unroll
    for (int it = 0; it < 2; ++it) {
        int q = tid + it * MT;
        int r = q >> 5, j = q & 31;
        int grow = row0 + r;
        float4 va = make_float4(0.f, 0.f, 0.f, 0.f);
        float4 vb = va;
        if (j < 8) {
            const float4* p = (const float4*)(user_emb + (size_t)user[grow] * 64);
            va = p[j * 2]; vb = p[j * 2 + 1];
        } else if (j < 16) {
            const float4* p = (const float4*)(item_emb + (size_t)item[grow] * 64);
            va = p[(j - 8) * 2]; vb = p[(j - 8) * 2 + 1];
        } else if (j == 16) {
            const float4* p = (const float4*)(genre + (size_t)grow * 20);
            va = p[0]; vb = p[1];
        } else if (j == 17) {
            const float4* p = (const float4*)(genre + (size_t)grow * 20);
            va = p[2]; vb = p[3];
        } else if (j == 18) {
            va = *(const float4*)(genre + (size_t)grow * 20 + 16);
            vb = *(const float4*)(tag + (size_t)grow * 100);
        } else if (j < 31) {
            const float4* p = (const float4*)(tag + (size_t)grow * 100 + 4);
            int jj = j - 19;
            va = p[jj * 2]; vb = p[jj * 2 + 1];
        } // j == 31: zero pad (k 248..255)
        // chunk (row=r, kc=j>>2, lh=j&3, lr=r&15) -> frag-major slot
        int slot = (((r >> 4) * 8 + (j >> 2)) << 6) + ((j & 3) << 4) + (r & 15);
        *(short8*)(sX + FSLOT(slot)) = cvt8(va, vb);
    }
    {
        int r = tid >> 4, j = tid & 15;
        int grow = row0 + r;
        float4 a = ((const float4*)(wide_W + (size_t)user[grow] * 64))[j];
        float4 b = ((const float4*)(wide_W + (size_t)(NU + item[grow]) * 64))[j];
        float4 c = ((const float4*)wide_b)[j];
        short4v o;
        o[0] = (short)f32_bf16(a.x + b.x + c.x);
        o[1] = (short)f32_bf16(a.y + b.y + c.y);
        o[2] = (short)f32_bf16(a.z + b.z + c.z);
        o[3] = (short)f32_bf16(a.w + b.w + c.w);
        *(short4v*)(sWide + r * 72 + j * 4) = o;
    }
    if (tid < 160) {
        ((float4*)sFW)[tid] = ((const float4*)fW)[tid];
    }
    __syncthreads();

    // ---- Layer 0: x[64][256] @ W0t -> h0[64][256] (wave = 16-col strip) ----
    {
        // Per-lane h0-write constants: n = cb0 + lr (col), elem n&7 in 16B chunk.
        const int n0_ = cb0 + lr;
        const int wkc = n0_ >> 5, wlh = (n0_ >> 3) & 3, wel = n0_ & 7;
        f32x4 acc[4];
        #pragma unroll
        for (int rt = 0; rt < 4; ++rt) acc[rt] = (f32x4)(0.f);
        #pragma unroll
        for (int kc = 0; kc < 8; ++kc) {
            #pragma unroll
            for (int rt = 0; rt < 4; ++rt) {
                short8 a = *(const short8*)(sX + rt * 9216 + kc * 1152 + aoff);
                acc[rt] = __builtin_amdgcn_mfma_f32_16x16x32_bf16(a, B0[kc], acc[rt], 0, 0, 0);
            }
        }
        #pragma unroll
        for (int rt = 0; rt < 4; ++rt)
            #pragma unroll
            for (int jj = 0; jj < 4; ++jj) {
                int rlo = lh * 4 + jj;              // row & 15 (rows rt*16 + rlo)
                float v = fmaxf(acc[rt][jj] + rb0, 0.f);
                int slot = ((rt * 8 + wkc) << 6) + (wlh << 4) + rlo;
                *(unsigned short*)(sH0 + FSLOT(slot) + wel * 2) = f32_bf16(v);
            }
        __syncthreads();
    }

    // ---- Layer 1: h0[64][256] @ W1t -> h1[64][128] (wave = 16-col x 32-row half) ----
    {
        const int n1_ = cb1 + lr;
        const int wkc = n1_ >> 5, wlh = (n1_ >> 3) & 3, wel = n1_ & 7;
        f32x4 acc[2];
        acc[0] = (f32x4)(0.f); acc[1] = (f32x4)(0.f);
        #pragma unroll
        for (int kc = 0; kc < 8; ++kc) {
            short8 bf = *(const short8*)(w1t + (size_t)(cb1 + lr) * 256 + kc * 32 + lh * 8);
            #pragma unroll
            for (int rt = 0; rt < 2; ++rt) {
                int rt2 = h1 * 2 + rt;
                short8 a = *(const short8*)(sH0 + rt2 * 9216 + kc * 1152 + aoff);
                acc[rt] = __builtin_amdgcn_mfma_f32_16x16x32_bf16(a, bf, acc[rt], 0, 0, 0);
            }
        }
        #pragma unroll
        for (int rt = 0; rt < 2; ++rt)
            #pragma unroll
            for (int jj = 0; jj < 4; ++jj) {
                int rt2 = h1 * 2 + rt;
                int rlo = lh * 4 + jj;
                float v = fmaxf(acc[rt][jj] + rb1, 0.f);
                int slot = ((rt2 * 4 + wkc) << 6) + (wlh << 4) + rlo;
                *(unsigned short*)(sH1 + FSLOT(slot) + wel * 2) = f32_bf16(v);
            }
        __syncthreads();
    }

    // ---- Layer 2: h1[64][128] @ W2t -> h2[64][64] (wave = 16-col x 16-row quarter) ----
    {
        f32x4 acc = (f32x4)(0.f);
        #pragma unroll
        for (int kc = 0; kc < 4; ++kc) {
            short8 bf = *(const short8*)(w2t + (size_t)(cb2 + lr) * 128 + kc * 32 + lh * 8);
            short8 a = *(const short8*)(sH1 + q2 * 4608 + kc * 1152 + aoff);
            acc = __builtin_amdgcn_mfma_f32_16x16x32_bf16(a, bf, acc, 0, 0, 0);
        }
        #pragma unroll
        for (int jj = 0; jj < 4; ++jj) {
            int row = q2 * 16 + lh * 4 + jj;
            sH2[row * 72 + cb2 + lr] = f32_bf16(fmaxf(acc[jj] + rb2, 0.f));
        }
        __syncthreads();
    }

    // ---- Final: [h2 | wide] @ fW + fb (fp32 VALU, LDS reads) ----
    if (tid < TBR * 5) {
        int r = tid / 5, c = tid - r * 5;
        float acc = fb[c];
        #pragma unroll
        for (int kq = 0; kq < 8; ++kq) {
            short8 h = *(const short8*)(sH2 + r * 72 + kq * 8);
            #pragma unroll
            for (int i = 0; i < 8; ++i)
                acc = fmaf(bf16_f32((unsigned short)h[i]), sFW[(kq * 8 + i) * 5 + c], acc);
        }
        #pragma unroll
        for (int kq = 0; kq < 8; ++kq) {
            short8 h = *(const short8*)(sWide + r * 72 + kq * 8);
            #pragma unroll
            for (int i = 0; i < 8; ++i)
                acc = fmaf(bf16_f32((unsigned short)h[i]), sFW[(64 + kq * 8 + i) * 5 + c], acc);
        }
        out[(size_t)(row0 + r) * 5 + c] = acc;
    }
}

// ================= fp32 fallback (used if ws too small) =================
#define NTHR 256
#define TB 32

__device__ __forceinline__ void fma4(float4& a, float s, const float4& w) {
    a.x = fmaf(s, w.x, a.x); a.y = fmaf(s, w.y, a.y);
    a.z = fmaf(s, w.z, a.z); a.w = fmaf(s, w.w, a.w);
}
__device__ __forceinline__ float4 add4(const float4& a, const float4& b) {
    return make_float4(a.x + b.x, a.y + b.y, a.z + b.z, a.w + b.w);
}
__device__ __forceinline__ float4 relu4(const float4& a) {
    return make_float4(fmaxf(a.x, 0.f), fmaxf(a.y, 0.f), fmaxf(a.z, 0.f), fmaxf(a.w, 0.f));
}

__global__ void wd_fused(const int* __restrict__ user, const int* __restrict__ item,
                         const float* __restrict__ genre, const float* __restrict__ tag,
                         const float* __restrict__ wide_W, const float* __restrict__ wide_b,
                         const float* __restrict__ user_emb, const float* __restrict__ item_emb,
                         const float* __restrict__ W0, const float* __restrict__ b0,
                         const float* __restrict__ W1, const float* __restrict__ b1,
                         const float* __restrict__ W2, const float* __restrict__ b2,
                         const float* __restrict__ fW, const float* __restrict__ fb,
                         float* __restrict__ out)
{
    __shared__ float sA[TB * 248];
    __shared__ float sB[TB * 256];
    __shared__ float sC[TB * 64];

    const int tid = threadIdx.x;
    const int row0 = blockIdx.x * TB;

    for (int q = tid; q < TB * 62; q += NTHR) {
        int r = q / 62, j = q - r * 62, grow = row0 + r;
        float4 v;
        if (j < 16) v = reinterpret_cast<const float4*>(user_emb + (size_t)user[grow] * 64)[j];
        else if (j < 32) v = reinterpret_cast<const float4*>(item_emb + (size_t)item[grow] * 64)[j - 16];
        else if (j < 37) v = reinterpret_cast<const float4*>(genre + (size_t)grow * 20)[j - 32];
        else v = reinterpret_cast<const float4*>(tag + (size_t)grow * 100)[j - 37];
        *reinterpret_cast<float4*>(sA + r * 248 + j * 4) = v;
    }
    for (int q = tid; q < TB * 16; q += NTHR) {
        int r = q >> 4, j = q & 15, grow = row0 + r;
        float4 a = reinterpret_cast<const float4*>(wide_W + (size_t)user[grow] * 64)[j];
        float4 b = reinterpret_cast<const float4*>(wide_W + (size_t)(NU + item[grow]) * 64)[j];
        float4 c = reinterpret_cast<const float4*>(wide_b)[j];
        *reinterpret_cast<float4*>(sC + r * 64 + j * 4) =
            make_float4(a.x + b.x + c.x, a.y + b.y + c.y, a.z + b.z + c.z, a.w + b.w + c.w);
    }
    __syncthreads();
    {
        const int cg = tid & 63, r0 = (tid >> 6) * 8;
        float4 acc[8];
        #pragma unroll
        for (int r = 0; r < 8; ++r) acc[r] = make_float4(0.f, 0.f, 0.f, 0.f);
        for (int k = 0; k < 248; k += 4) {
            const float4* wp = reinterpret_cast<const float4*>(W0 + (size_t)k * 256) + cg;
            float4 w0 = wp[0], w1 = wp[64], w2 = wp[128], w3 = wp[192];
            #pragma unroll
            for (int r = 0; r < 8; ++r) {
                float4 xv = *reinterpret_cast<const float4*>(sA + (r0 + r) * 248 + k);
                fma4(acc[r], xv.x, w0); fma4(acc[r], xv.y, w1);
                fma4(acc[r], xv.z, w2); fma4(acc[r], xv.w, w3);
            }
        }
        float4 bb = reinterpret_cast<const float4*>(b0)[cg];
        #pragma unroll
        for (int r = 0; r < 8; ++r)
            *reinterpret_cast<float4*>(sB + (r0 + r) * 256 + cg * 4) = relu4(add4(acc[r], bb));
    }
    __syncthreads();
    {
        const int cg = tid & 31, r0 = (tid >> 5) * 4;
        float4 acc[4];
        #pragma unroll
        for (int r = 0; r < 4; ++r) acc[r] = make_float4(0.f, 0.f, 0.f, 0.f);
        for (int k = 0; k < 256; k += 4) {
            const float4* wp = reinterpret_cast<const float4*>(W1 + (size_t)k * 128) + cg;
            float4 w0 = wp[0], w1 = wp[32], w2 = wp[64], w3 = wp[96];
            #pragma unroll
            for (int r = 0; r < 4; ++r) {
                float4 xv = *reinterpret_cast<const float4*>(sB + (r0 + r) * 256 + k);
                fma4(acc[r], xv.x, w0); fma4(acc[r], xv.y, w1);
                fma4(acc[r], xv.z, w2); fma4(acc[r], xv.w, w3);
            }
        }
        float4 bb = reinterpret_cast<const float4*>(b1)[cg];
        #pragma unroll
        for (int r = 0; r < 4; ++r)
            *reinterpret_cast<float4*>(sA + (r0 + r) * 128 + cg * 4) = relu4(add4(acc[r], bb));
    }
    __syncthreads();
    {
        const int cg = tid & 15, r0 = (tid >> 4) * 2;
        float4 acc[2];
        acc[0] = make_float4(0.f, 0.f, 0.f, 0.f); acc[1] = acc[0];
        for (int k = 0; k < 128; k += 4) {
            const float4* wp = reinterpret_cast<const float4*>(W2 + (size_t)k * 64) + cg;
            float4 w0 = wp[0], w1 = wp[16], w2 = wp[32], w3 = wp[48];
            #pragma unroll
            for (int r = 0; r < 2; ++r) {
                float4 xv = *reinterpret_cast<const float4*>(sA + (r0 + r) * 128 + k);
                fma4(acc[r], xv.x, w0); fma4(acc[r], xv.y, w1);
                fma4(acc[r], xv.z, w2); fma4(acc[r], xv.w, w3);
            }
        }
        float4 bb = reinterpret_cast<const float4*>(b2)[cg];
        #pragma unroll
        for (int r = 0; r < 2; ++r)
            *reinterpret_cast<float4*>(sB + (r0 + r) * 64 + cg * 4) = relu4(add4(acc[r], bb));
    }
    __syncthreads();
    if (tid < TB * 5) {
        int r = tid / 5, c = tid - r * 5;
        float acc = fb[c];
        for (int k = 0; k < 64; ++k) acc = fmaf(sB[r * 64 + k], fW[k * 5 + c], acc);
        for (int k = 0; k < 64; ++k) acc = fmaf(sC[r * 64 + k], fW[(64 + k) * 5 + c], acc);
        out[(size_t)(row0 + r) * 5 + c] = acc;
    }
}

extern "C" void kernel_launch(void* const* d_in, const int* in_sizes, int n_in,
                              void* d_out, int out_size, void* d_ws, size_t ws_size,
                              hipStream_t stream) {
    const int* user = (const int*)d_in[0];
    const int* item = (const int*)d_in[1];
    const float* genre = (const float*)d_in[2];
    const float* tag = (const float*)d_in[3];
    const float* wide_W = (const float*)d_in[4];
    const float* wide_b = (const float*)d_in[5];
    const float* user_emb = (const float*)d_in[6];
    const float* item_emb = (const float*)d_in[7];
    const float* W0 = (const float*)d_in[8];
    const float* b0 = (const float*)d_in[9];
    const float* W1 = (const float*)d_in[10];
    const float* b1 = (const float*)d_in[11];
    const float* W2 = (const float*)d_in[12];
    const float* b2 = (const float*)d_in[13];
    const float* fW = (const float*)d_in[14];
    const float* fb = (const float*)d_in[15];
    float* out = (float*)d_out;

    if (ws_size >= (size_t)WSREQ) {
        unsigned short* ws = (unsigned short*)d_ws;
        hipLaunchKernelGGL(prep_simple, dim3(104), dim3(512), 0, stream,
                           W0, W1, W2, ws);
        hipLaunchKernelGGL(wd_mfma, dim3(BATCH / TBR), dim3(MT), 0, stream,
                           user, item, genre, tag, wide_W, wide_b, user_emb, item_emb,
                           b0, b1, b2, fW, fb, ws, out);
    } else {
        hipLaunchKernelGGL(wd_fused, dim3(BATCH / TB), dim3(NTHR), 0, stream,
                           user, item, genre, tag, wide_W, wide_b, user_emb, item_emb,
                           W0, b0, W1, b1, W2, b2, fW, fb, out);
    }
}